// Round 4
// baseline (87.678 us; speedup 1.0000x reference)
//
#include <hip/hip_runtime.h>
#include <math.h>

#define NIMG 64
#define HW   1024
#define NCH  85
#define NCLS 80
#define NW   16     // waves per NMS block
#define CPW  5      // classes per wave (16*5 = 80)
#define CONF_TH 0.25f
#define NMS_TH  0.35f

__device__ __forceinline__ float fast_tanh(float x) {
  float e = __expf(2.0f * x);
  return 1.0f - 2.0f * __builtin_amdgcn_rcpf(e + 1.0f);
}
__device__ __forceinline__ float fast_sigmoid(float x) {
  return __builtin_amdgcn_rcpf(1.0f + __expf(-x));
}

// ---------------------------------------------------------------------------
// Decode kernel (verbatim from the 73.8us round-1 version): one thread per
// pixel, 256 blocks x 256 threads (all 256 CUs). Fully-coalesced loads; 4
// independent 20-class argmax chains; ascending merge with strict '>' ==
// exact first-occurrence argmax. Also zeroes keepOut.
// ---------------------------------------------------------------------------
__global__ __launch_bounds__(256) void decode_kernel(const float* __restrict__ preds,
                                                     float* __restrict__ out,
                                                     float* __restrict__ keepOut) {
  int gid = blockIdx.x * 256 + threadIdx.x;   // 0 .. 65535
  int n = gid >> 10;
  int t = gid & 1023;
  const float* bp = preds + (size_t)n * (NCH * HW) + t;

  float pobj = bp[0];
  float tx = bp[(size_t)1 * HW];
  float ty = bp[(size_t)2 * HW];
  float tw = bp[(size_t)3 * HW];
  float th = bp[(size_t)4 * HW];

  float b0, b1, b2, b3;
  int i0, i1, i2, i3;
  b0 = bp[(size_t)(5 +  0) * HW]; i0 =  0;
  b1 = bp[(size_t)(5 + 20) * HW]; i1 = 20;
  b2 = bp[(size_t)(5 + 40) * HW]; i2 = 40;
  b3 = bp[(size_t)(5 + 60) * HW]; i3 = 60;
#pragma unroll
  for (int c = 1; c < 20; ++c) {
    float v0 = bp[(size_t)(5 +  0 + c) * HW];
    float v1 = bp[(size_t)(5 + 20 + c) * HW];
    float v2 = bp[(size_t)(5 + 40 + c) * HW];
    float v3 = bp[(size_t)(5 + 60 + c) * HW];
    if (v0 > b0) { b0 = v0; i0 =  0 + c; }
    if (v1 > b1) { b1 = v1; i1 = 20 + c; }
    if (v2 > b2) { b2 = v2; i2 = 40 + c; }
    if (v3 > b3) { b3 = v3; i3 = 60 + c; }
  }
  float best = b0; int bc = i0;
  if (b1 > best) { best = b1; bc = i1; }
  if (b2 > best) { best = b2; bc = i2; }
  if (b3 > best) { best = b3; bc = i3; }

  float score = pobj * best;                 // bit-exact vs reference

  float gx = (float)(t & 31);
  float gy = (float)(t >> 5);
  float bcx = (fast_tanh(tx) + gx) * 0.03125f;
  float bcy = (fast_tanh(ty) + gy) * 0.03125f;
  float bw = fast_sigmoid(tw);
  float bh = fast_sigmoid(th);

  float x1 = bcx - 0.5f * bw, y1 = bcy - 0.5f * bh;
  float x2 = bcx + 0.5f * bw, y2 = bcy + 0.5f * bh;

  float2* ob = (float2*)(out + (size_t)gid * 6);
  ob[0] = make_float2(x1, y1);
  ob[1] = make_float2(x2, y2);
  ob[2] = make_float2(score, (float)bc);

  keepOut[gid] = 0.0f;
}

// ---------------------------------------------------------------------------
// Wave-local NMS: one block per image, 1024 threads, 16 waves x 5 classes.
// One barrier total; no atomics; no block-wide phase ladder. SPILL-PROOF:
// no per-lane register arrays — all per-pixel state lives in LDS and is
// re-read (stride-64 lane pattern = 2 lanes/bank = conflict-free).
// Member list built cooperatively via ballot+popc prefix (exact
// pixel-ascending order); rank & greedy math identical to the verified
// reference semantics (stable sort, ref IoU op order, strict >).
// ---------------------------------------------------------------------------
__global__ __launch_bounds__(1024) void nms_kernel(const float* __restrict__ boxes,
                                                   float* __restrict__ keepOut) {
  int n = blockIdx.x;
  int t = threadIdx.x;
  int wv   = t >> 6;        // wave id 0..15
  int lane = t & 63;

  __shared__ float sx1[HW], sy1[HW], sx2[HW], sy2[HW], sarea[HW], sscore[HW];
  __shared__ int scls[HW];
  __shared__ unsigned short mlist[NW][HW];      // per-wave member list (pixel-asc)
  __shared__ unsigned short ssort[NW][64];      // per-wave rank->pixel (fast path)
  __shared__ unsigned long long wflags[NW][32]; // fallback: processed[0:16), kept[16:32)

  // ---- stage this image's decoded boxes: 1 box per thread ----
  size_t gb = (size_t)n * HW + t;
  const float2* ib = (const float2*)(boxes + gb * 6);
  float2 a01 = ib[0];
  float2 a23 = ib[1];
  float2 a45 = ib[2];
  sx1[t] = a01.x; sy1[t] = a01.y; sx2[t] = a23.x; sy2[t] = a23.y;
  sarea[t] = (a23.x - a01.x) * (a23.y - a01.y);
  sscore[t] = a45.x;
  scls[t] = (int)a45.y;
  __syncthreads();                              // the only barrier

  // ---- wave wv owns classes 5*wv .. 5*wv+4, fully independently ----
  for (int ci = 0; ci < CPW; ++ci) {
    int c = wv * CPW + ci;

    // -- collect members in pixel-ascending order (ballot + prefix-popc) --
    int m = 0;
#pragma unroll
    for (int k = 0; k < 16; ++k) {
      int p = (k << 6) | lane;
      bool pred = (scls[p] == c) && (sscore[p] > CONF_TH);
      unsigned long long mask = __ballot(pred);
      if (pred) {
        int prefix = __popcll(mask & ((1ull << lane) - 1ull));
        mlist[wv][m + prefix] = (unsigned short)p;
      }
      m += __popcll(mask);                      // uniform across the wave
    }
    if (m == 0) continue;

    if (m <= 64) {
      // -- rank: lane j owns member j; exact stable (score desc, idx asc) --
      bool active = (lane < m);
      int pj = 0; float scj = 0.0f; int rj = 0;
      if (active) { pj = mlist[wv][lane]; scj = sscore[pj]; }
      for (int i = 0; i < m; ++i) {
        int pi = mlist[wv][i];                  // uniform LDS read (broadcast)
        float si = sscore[pi];
        if (active) rj += (si > scj) || (si == scj && pi < pj);
      }
      if (active) ssort[wv][rj] = (unsigned short)pj;

      // -- lane b caches the rank-b box (5 scalars, no arrays) --
      float kx1 = 0, ky1 = 0, kx2 = 0, ky2 = 0, kar = 0;
      if (active) {
        int qb = ssort[wv][lane];
        kx1 = sx1[qb]; ky1 = sy1[qb]; kx2 = sx2[qb]; ky2 = sy2[qb]; kar = sarea[qb];
      }

      // -- greedy scan in rank order: lane-parallel IoU vs kept, ballot --
      unsigned long long kept = 0ull;           // uniform in every lane
      for (int a = 0; a < m; ++a) {
        int qa = ssort[wv][a];                  // uniform broadcast read
        float ax1 = sx1[qa], ay1 = sy1[qa], ax2 = sx2[qa], ay2 = sy2[qa];
        float aar = sarea[qa];                  // candidate area (first in denom)
        bool sup = false;
        if (lane < a && ((kept >> lane) & 1ull)) {
          float iw = fminf(ax2, kx2) - fmaxf(ax1, kx1);
          float ih = fminf(ay2, ky2) - fmaxf(ay1, ky1);
          iw = fmaxf(iw, 0.0f);
          ih = fmaxf(ih, 0.0f);
          float inter = iw * ih;
          float iou = inter / (aar + kar - inter + 1e-9f);  // exact ref op order
          sup = iou > NMS_TH;
        }
        unsigned long long v = __ballot(sup);
        if (v == 0ull) {
          kept |= (1ull << a);
          if (lane == 0) keepOut[(size_t)n * HW + qa] = 1.0f;
        }
      }
    } else {
      // -- capacity-complete exact fallback (Poisson mean ~6: never expected) --
      if (lane == 0) {
        for (int i = 0; i < 32; ++i) wflags[wv][i] = 0ull;
        for (int a = 0; a < m; ++a) {
          int bj = -1; float bs = 0.0f; int bpx = 0;
          for (int j = 0; j < m; ++j) {
            if ((wflags[wv][j >> 6] >> (j & 63)) & 1ull) continue;
            int pj2 = mlist[wv][j];
            float sj2 = sscore[pj2];
            if (bj < 0 || sj2 > bs || (sj2 == bs && pj2 < bpx)) { bj = j; bs = sj2; bpx = pj2; }
          }
          wflags[wv][bj >> 6] |= 1ull << (bj & 63);
          float cx1 = sx1[bpx], cy1 = sy1[bpx], cx2 = sx2[bpx], cy2 = sy2[bpx];
          float car = sarea[bpx];
          bool kp = true;
          for (int j = 0; j < m && kp; ++j) {
            if (!((wflags[wv][16 + (j >> 6)] >> (j & 63)) & 1ull)) continue;
            int pj2 = mlist[wv][j];
            float iw = fminf(cx2, sx2[pj2]) - fmaxf(cx1, sx1[pj2]);
            float ih = fminf(cy2, sy2[pj2]) - fmaxf(cy1, sy1[pj2]);
            iw = fmaxf(iw, 0.0f);
            ih = fmaxf(ih, 0.0f);
            float inter = iw * ih;
            float iou = inter / (car + sarea[pj2] - inter + 1e-9f);
            if (iou > NMS_TH) kp = false;
          }
          if (kp) {
            wflags[wv][16 + (bj >> 6)] |= 1ull << (bj & 63);
            keepOut[(size_t)n * HW + bpx] = 1.0f;
          }
        }
      }
    }
  }
}

extern "C" void kernel_launch(void* const* d_in, const int* in_sizes, int n_in,
                              void* d_out, int out_size, void* d_ws, size_t ws_size,
                              hipStream_t stream) {
  const float* preds = (const float*)d_in[0];
  float* out = (float*)d_out;
  float* keepOut = out + (size_t)NIMG * HW * 6;

  decode_kernel<<<NIMG * HW / 256, 256, 0, stream>>>(preds, out, keepOut);
  nms_kernel<<<NIMG, HW, 0, stream>>>(out, keepOut);
}